// Round 1
// baseline (459.779 us; speedup 1.0000x reference)
//
#include <hip/hip_runtime.h>

typedef __attribute__((ext_vector_type(8))) __bf16 bf16x8;
typedef __attribute__((ext_vector_type(4))) float f32x4;

constexpr int T  = 4096;   // tokens
constexpr int Dm = 1024;   // model dim
constexpr int Hm = 4096;   // hidden dim
constexpr int NE = 8;      // experts
constexpr int CAP = 1075;  // capacity  round(2*4096*1.05/8)
constexpr int CP  = 1152;  // capacity padded to 9*128

static __device__ __forceinline__ unsigned short f2bf(float f) {
  unsigned int u = __float_as_uint(f);
  u += 0x7FFFu + ((u >> 16) & 1u);   // RNE (NaN-unsafe, inputs are finite)
  return (unsigned short)(u >> 16);
}

// ---------------- router: logits = x @ Wg^T, softmax, top-2 ----------------
__global__ __launch_bounds__(256) void router_kernel(
    const float* __restrict__ x, const float* __restrict__ Wg,
    int* __restrict__ topi, float* __restrict__ topw) {
  int t = blockIdx.x * 4 + (threadIdx.x >> 6);
  int lane = threadIdx.x & 63;
  const float* xr = x + (size_t)t * Dm;
  float acc[NE];
#pragma unroll
  for (int e = 0; e < NE; ++e) acc[e] = 0.f;
  for (int i = lane * 4; i < Dm; i += 256) {
    float4 xv = *(const float4*)(xr + i);
#pragma unroll
    for (int e = 0; e < NE; ++e) {
      float4 wv = *(const float4*)(Wg + e * Dm + i);
      acc[e] += xv.x * wv.x + xv.y * wv.y + xv.z * wv.z + xv.w * wv.w;
    }
  }
#pragma unroll
  for (int off = 32; off > 0; off >>= 1) {
#pragma unroll
    for (int e = 0; e < NE; ++e) acc[e] += __shfl_xor(acc[e], off, 64);
  }
  if (lane == 0) {
    float mx = acc[0];
#pragma unroll
    for (int e = 1; e < NE; ++e) mx = fmaxf(mx, acc[e]);
    float g[NE];
    float s = 0.f;
#pragma unroll
    for (int e = 0; e < NE; ++e) { g[e] = expf(acc[e] - mx); s += g[e]; }
    // top-2 over gates, ties -> lower index (matches jax.lax.top_k)
    int i0 = 0; float v0 = g[0];
#pragma unroll
    for (int e = 1; e < NE; ++e) if (g[e] > v0) { v0 = g[e]; i0 = e; }
    int i1 = -1; float v1 = -1e30f;
#pragma unroll
    for (int e = 0; e < NE; ++e) {
      if (e == i0) continue;
      if (g[e] > v1) { v1 = g[e]; i1 = e; }
    }
    float inv = 1.f / s;
    topi[t * 2] = i0; topi[t * 2 + 1] = i1;
    topw[t * 2] = v0 * inv; topw[t * 2 + 1] = v1 * inv;
  }
}

// ------------- dispatch: slot-major cumulative count per expert -------------
// assignment a = k*T + t  (k-major, exactly topi.T.reshape(-1))
__global__ void dispatch_kernel(const int* __restrict__ topi,
                                int* __restrict__ pos, int* __restrict__ within) {
  int lane = threadIdx.x;  // blockDim = 64, one wave
  int cnt[NE];
#pragma unroll
  for (int e = 0; e < NE; ++e) cnt[e] = 0;
  unsigned long long below = (1ULL << lane) - 1ULL;
  for (int c = 0; c < (2 * T) / 64; ++c) {
    int a = c * 64 + lane;
    int k = a >> 12;        // a / T
    int t = a & (T - 1);
    int e = topi[t * 2 + k];
    int p = 0;
#pragma unroll
    for (int ex = 0; ex < NE; ++ex) {
      unsigned long long m = __ballot(e == ex);
      if (e == ex) p = cnt[ex] + __popcll(m & below);
      cnt[ex] += __popcll(m);
    }
    pos[a] = p;
    within[a] = (p < CAP) ? 1 : 0;
  }
}

// ---------------- scatter accepted tokens -> buf[e][p] (bf16) ----------------
__global__ __launch_bounds__(256) void scatter_kernel(
    const float* __restrict__ x, const int* __restrict__ topi,
    const int* __restrict__ pos, const int* __restrict__ within,
    unsigned short* __restrict__ buf) {
  int a = blockIdx.x;
  if (!within[a]) return;
  int k = a >> 12, t = a & (T - 1);
  int e = topi[t * 2 + k];
  int p = pos[a];
  const float* src = x + (size_t)t * Dm;
  unsigned short* dst = buf + ((size_t)e * CP + p) * Dm;
  int i = threadIdx.x * 4;
  float4 v = *(const float4*)(src + i);
  ushort4 o;
  o.x = f2bf(v.x); o.y = f2bf(v.y); o.z = f2bf(v.z); o.w = f2bf(v.w);
  *(ushort4*)(dst + i) = o;
}

// ---------------- grouped GEMM: C = A(bf16) @ B(fp32->bf16) + bias ----------------
// 128x128 tile, BK=32, 4 waves of 64x64, mfma_f32_16x16x32_bf16
template <bool GELU, bool OUT_BF16>
__global__ __launch_bounds__(256) void gemm_kernel(
    const unsigned short* __restrict__ Aall, const float* __restrict__ Ball,
    const float* __restrict__ biasAll, void* __restrict__ OutAll,
    int Kd, int N, long long sA, long long sB, long long sO, int sBias) {
  __shared__ unsigned short Alds[128][40];
  __shared__ unsigned short Blds[128][40];  // [n][k], transposed during staging

  const int e = blockIdx.z;
  const unsigned short* A = Aall + (long long)e * sA + (long long)blockIdx.y * 128 * Kd;
  const float* B = Ball + (long long)e * sB + blockIdx.x * 128;
  const float* bias = biasAll + (long long)e * sBias + blockIdx.x * 128;

  const int tid = threadIdx.x;
  const int lane = tid & 63;
  const int wid = tid >> 6;
  const int wr = (wid >> 1) * 64;
  const int wc = (wid & 1) * 64;
  const int l15 = lane & 15;
  const int lk8 = (lane >> 4) * 8;

  f32x4 acc[4][4];
#pragma unroll
  for (int m = 0; m < 4; ++m)
#pragma unroll
    for (int n = 0; n < 4; ++n) acc[m][n] = (f32x4){0.f, 0.f, 0.f, 0.f};

  const int ar = tid >> 2;        // 0..63
  const int ak = (tid & 3) * 8;   // 0,8,16,24
  const int bn = (tid & 63) * 2;  // 0..126 even
  const int bk0 = (tid >> 6) * 4; // 0,4,8,12

  const int nK = Kd >> 5;
  for (int kt = 0; kt < nK; ++kt) {
    const int kb = kt << 5;
    // global loads first (overlap with barrier)
    int4 a0 = *(const int4*)(A + (long long)ar * Kd + kb + ak);
    int4 a1 = *(const int4*)(A + (long long)(ar + 64) * Kd + kb + ak);
    float2 bv[2][4];
#pragma unroll
    for (int pp = 0; pp < 2; ++pp) {
      const float* src = B + (long long)(kb + bk0 + pp * 16) * N + bn;
#pragma unroll
      for (int r = 0; r < 4; ++r) bv[pp][r] = *(const float2*)(src + (long long)r * N);
    }
    __syncthreads();  // previous iter's reads done
    *(int4*)&Alds[ar][ak] = a0;
    *(int4*)&Alds[ar + 64][ak] = a1;
#pragma unroll
    for (int pp = 0; pp < 2; ++pp) {
      int bk = bk0 + pp * 16;
      ushort4 w0, w1;
      w0.x = f2bf(bv[pp][0].x); w0.y = f2bf(bv[pp][1].x);
      w0.z = f2bf(bv[pp][2].x); w0.w = f2bf(bv[pp][3].x);
      w1.x = f2bf(bv[pp][0].y); w1.y = f2bf(bv[pp][1].y);
      w1.z = f2bf(bv[pp][2].y); w1.w = f2bf(bv[pp][3].y);
      *(ushort4*)&Blds[bn][bk] = w0;
      *(ushort4*)&Blds[bn + 1][bk] = w1;
    }
    __syncthreads();
    bf16x8 af[4], bfv[4];
#pragma unroll
    for (int m = 0; m < 4; ++m)
      af[m] = *(const bf16x8*)&Alds[wr + m * 16 + l15][lk8];
#pragma unroll
    for (int n = 0; n < 4; ++n)
      bfv[n] = *(const bf16x8*)&Blds[wc + n * 16 + l15][lk8];
#pragma unroll
    for (int m = 0; m < 4; ++m)
#pragma unroll
      for (int n = 0; n < 4; ++n)
        acc[m][n] = __builtin_amdgcn_mfma_f32_16x16x32_bf16(af[m], bfv[n], acc[m][n], 0, 0, 0);
  }

  // epilogue: bias (+ exact GELU), store
  const int crow = (lane >> 4) * 4;
#pragma unroll
  for (int m = 0; m < 4; ++m) {
#pragma unroll
    for (int n = 0; n < 4; ++n) {
      const long long col = (long long)blockIdx.x * 128 + wc + n * 16 + l15;
      const float bvv = bias[wc + n * 16 + l15];
#pragma unroll
      for (int j = 0; j < 4; ++j) {
        const long long row = (long long)blockIdx.y * 128 + wr + m * 16 + crow + j;
        float v = acc[m][n][j] + bvv;
        if (GELU) v = 0.5f * v * (1.f + erff(v * 0.70710678118654752f));
        if (OUT_BF16)
          ((unsigned short*)OutAll)[(long long)e * sO + row * N + col] = f2bf(v);
        else
          ((float*)OutAll)[(long long)e * sO + row * N + col] = v;
      }
    }
  }
}

// ---------------- combine: out[t] = sum_k cw * y[e_k, p_k] ----------------
__global__ __launch_bounds__(256) void combine_kernel(
    const float* __restrict__ y, const int* __restrict__ topi,
    const float* __restrict__ topw, const int* __restrict__ pos,
    const int* __restrict__ within, float* __restrict__ out) {
  int t = blockIdx.x;
  int i = threadIdx.x * 4;
  float4 r = {0.f, 0.f, 0.f, 0.f};
#pragma unroll
  for (int k = 0; k < 2; ++k) {
    int a = k * T + t;
    if (within[a]) {  // guard (not multiply) -> never touch garbage rows
      int e = topi[t * 2 + k];
      int p = pos[a];
      float w = topw[t * 2 + k];
      const float* yr = y + ((size_t)e * CP + p) * Dm;
      float4 v = *(const float4*)(yr + i);
      r.x += w * v.x; r.y += w * v.y; r.z += w * v.z; r.w += w * v.w;
    }
  }
  *(float4*)(out + (size_t)t * Dm + i) = r;
}

extern "C" void kernel_launch(void* const* d_in, const int* in_sizes, int n_in,
                              void* d_out, int out_size, void* d_ws, size_t ws_size,
                              hipStream_t stream) {
  const float* x  = (const float*)d_in[0];
  const float* Wg = (const float*)d_in[1];
  const float* W1 = (const float*)d_in[2];
  const float* b1 = (const float*)d_in[3];
  const float* W2 = (const float*)d_in[4];
  const float* b2 = (const float*)d_in[5];
  float* out = (float*)d_out;

  // workspace layout (all 16B aligned)
  unsigned short* buf = (unsigned short*)d_ws;               // E*CP*Dm bf16   = 18.9 MB
  unsigned short* h   = buf + (size_t)NE * CP * Dm;          // E*CP*Hm bf16   = 75.5 MB
  float* y    = (float*)(h + (size_t)NE * CP * Hm);          // E*CP*Dm f32    = 37.7 MB
  int* topi   = (int*)(y + (size_t)NE * CP * Dm);            // 2T i32
  float* topw = (float*)(topi + 2 * T);                      // 2T f32
  int* pos    = (int*)(topw + 2 * T);                        // 2T i32
  int* within = pos + 2 * T;                                 // 2T i32

  router_kernel<<<T / 4, 256, 0, stream>>>(x, Wg, topi, topw);
  dispatch_kernel<<<1, 64, 0, stream>>>(topi, pos, within);
  scatter_kernel<<<2 * T, 256, 0, stream>>>(x, topi, pos, within, buf);

  // GEMM1: h = gelu(buf @ W1 + b1)   [E, CP, Hm] bf16
  gemm_kernel<true, true><<<dim3(Hm / 128, CP / 128, NE), 256, 0, stream>>>(
      buf, W1, b1, (void*)h, Dm, Hm,
      (long long)CP * Dm, (long long)Dm * Hm, (long long)CP * Hm, Hm);
  // GEMM2: y = h @ W2 + b2           [E, CP, Dm] f32
  gemm_kernel<false, false><<<dim3(Dm / 128, CP / 128, NE), 256, 0, stream>>>(
      h, W2, b2, (void*)y, Hm, Dm,
      (long long)CP * Hm, (long long)Hm * Dm, (long long)CP * Dm, Dm);

  combine_kernel<<<T, 256, 0, stream>>>(y, topi, topw, pos, within, out);
}

// Round 2
// 397.565 us; speedup vs baseline: 1.1565x; 1.1565x over previous
//
#include <hip/hip_runtime.h>

typedef __attribute__((ext_vector_type(8))) __bf16 bf16x8;
typedef __attribute__((ext_vector_type(4))) float f32x4;

constexpr int T  = 4096;   // tokens
constexpr int Dm = 1024;   // model dim
constexpr int Hm = 4096;   // hidden dim
constexpr int NE = 8;      // experts
constexpr int CAP = 1075;  // capacity  round(2*4096*1.05/8)
constexpr int CP  = 1152;  // capacity padded to 9*128

static __device__ __forceinline__ unsigned short f2bf(float f) {
  unsigned int u = __float_as_uint(f);
  u += 0x7FFFu + ((u >> 16) & 1u);   // RNE
  return (unsigned short)(u >> 16);
}

static __device__ __forceinline__ void gload_lds16(const void* g, void* l) {
  __builtin_amdgcn_global_load_lds(
      (const __attribute__((address_space(1))) void*)g,
      (__attribute__((address_space(3))) void*)l, 16, 0, 0);
}

// ---------------- router: logits = x @ Wg^T, softmax, top-2 ----------------
__global__ __launch_bounds__(256) void router_kernel(
    const float* __restrict__ x, const float* __restrict__ Wg,
    int* __restrict__ topi, float* __restrict__ topw) {
  int t = blockIdx.x * 4 + (threadIdx.x >> 6);
  int lane = threadIdx.x & 63;
  const float* xr = x + (size_t)t * Dm;
  float acc[NE];
#pragma unroll
  for (int e = 0; e < NE; ++e) acc[e] = 0.f;
  for (int i = lane * 4; i < Dm; i += 256) {
    float4 xv = *(const float4*)(xr + i);
#pragma unroll
    for (int e = 0; e < NE; ++e) {
      float4 wv = *(const float4*)(Wg + e * Dm + i);
      acc[e] += xv.x * wv.x + xv.y * wv.y + xv.z * wv.z + xv.w * wv.w;
    }
  }
#pragma unroll
  for (int off = 32; off > 0; off >>= 1) {
#pragma unroll
    for (int e = 0; e < NE; ++e) acc[e] += __shfl_xor(acc[e], off, 64);
  }
  if (lane == 0) {
    float mx = acc[0];
#pragma unroll
    for (int e = 1; e < NE; ++e) mx = fmaxf(mx, acc[e]);
    float g[NE];
    float s = 0.f;
#pragma unroll
    for (int e = 0; e < NE; ++e) { g[e] = expf(acc[e] - mx); s += g[e]; }
    int i0 = 0; float v0 = g[0];
#pragma unroll
    for (int e = 1; e < NE; ++e) if (g[e] > v0) { v0 = g[e]; i0 = e; }
    int i1 = -1; float v1 = -1e30f;
#pragma unroll
    for (int e = 0; e < NE; ++e) {
      if (e == i0) continue;
      if (g[e] > v1) { v1 = g[e]; i1 = e; }
    }
    float inv = 1.f / s;
    topi[t * 2] = i0; topi[t * 2 + 1] = i1;
    topw[t * 2] = v0 * inv; topw[t * 2 + 1] = v1 * inv;
  }
}

// ------------- dispatch: slot-major cumulative count per expert -------------
__global__ void dispatch_kernel(const int* __restrict__ topi,
                                int* __restrict__ pos, int* __restrict__ within) {
  int lane = threadIdx.x;  // one wave
  int cnt[NE];
#pragma unroll
  for (int e = 0; e < NE; ++e) cnt[e] = 0;
  unsigned long long below = (1ULL << lane) - 1ULL;
  for (int c = 0; c < (2 * T) / 64; ++c) {
    int a = c * 64 + lane;
    int k = a >> 12;
    int t = a & (T - 1);
    int e = topi[t * 2 + k];
    int p = 0;
#pragma unroll
    for (int ex = 0; ex < NE; ++ex) {
      unsigned long long m = __ballot(e == ex);
      if (e == ex) p = cnt[ex] + __popcll(m & below);
      cnt[ex] += __popcll(m);
    }
    pos[a] = p;
    within[a] = (p < CAP) ? 1 : 0;
  }
}

// ---------------- scatter accepted tokens -> buf[e][p] (bf16) ----------------
__global__ __launch_bounds__(256) void scatter_kernel(
    const float* __restrict__ x, const int* __restrict__ topi,
    const int* __restrict__ pos, const int* __restrict__ within,
    unsigned short* __restrict__ buf) {
  int a = blockIdx.x;
  if (!within[a]) return;
  int k = a >> 12, t = a & (T - 1);
  int e = topi[t * 2 + k];
  int p = pos[a];
  const float* src = x + (size_t)t * Dm;
  unsigned short* dst = buf + ((size_t)e * CP + p) * Dm;
  int i = threadIdx.x * 4;
  float4 v = *(const float4*)(src + i);
  ushort4 o;
  o.x = f2bf(v.x); o.y = f2bf(v.y); o.z = f2bf(v.z); o.w = f2bf(v.w);
  *(ushort4*)(dst + i) = o;
}

// ------------- transpose+convert: W [E?][Kd][N] f32 -> Wt [E?][N][Kd] bf16 -------------
__global__ __launch_bounds__(256) void transpose_kernel(
    const float* __restrict__ W, unsigned short* __restrict__ Wt,
    int Kd, int N) {
  __shared__ float tile[64][33];
  const int e = blockIdx.z;
  const int n0 = blockIdx.x * 32;
  const int k0 = blockIdx.y * 64;
  const float* src = W + ((long long)e * Kd + k0) * N + n0;
  const int tid = threadIdx.x;
  const int r = tid >> 3;            // 0..31
  const int c4 = (tid & 7) * 4;
#pragma unroll
  for (int hh = 0; hh < 2; ++hh) {
    float4 v = *(const float4*)(src + (long long)(r + 32 * hh) * N + c4);
    tile[r + 32 * hh][c4] = v.x; tile[r + 32 * hh][c4 + 1] = v.y;
    tile[r + 32 * hh][c4 + 2] = v.z; tile[r + 32 * hh][c4 + 3] = v.w;
  }
  __syncthreads();
  const int n = tid >> 4;            // 0..15
  const int k4 = (tid & 15) * 4;
  unsigned short* dst = Wt + ((long long)e * N + n0) * Kd + k0;
#pragma unroll
  for (int hh = 0; hh < 2; ++hh) {
    int nn = n + 16 * hh;
    ushort4 o;
    o.x = f2bf(tile[k4][nn]);     o.y = f2bf(tile[k4 + 1][nn]);
    o.z = f2bf(tile[k4 + 2][nn]); o.w = f2bf(tile[k4 + 3][nn]);
    *(ushort4*)(dst + (long long)nn * Kd + k4) = o;
  }
}

// ---------------- GEMM: C[M][N] = A[M][K](bf16) @ Bt[N][K](bf16)^T + bias ----------------
// m97 structure: 128x128 tile, BK=64, 4 waves of 64x64, global_load_lds w16,
// source-permuted LDS slots (slot ^= row&7) for conflict-free ds_read_b128.
template <bool GELU, bool OUT_BF16>
__global__ __launch_bounds__(256) void gemm_bt_kernel(
    const unsigned short* __restrict__ Aall, const unsigned short* __restrict__ Btall,
    const float* __restrict__ biasAll, void* __restrict__ OutAll,
    int Kd, int N, long long sA, long long sB, long long sO, int sBias) {
  __shared__ unsigned short Alds[128 * 64];
  __shared__ unsigned short Blds[128 * 64];

  const int e = blockIdx.z;
  const unsigned short* A  = Aall  + (long long)e * sA + (long long)blockIdx.y * 128 * Kd;
  const unsigned short* Bt = Btall + (long long)e * sB + (long long)blockIdx.x * 128 * Kd;
  const float* bias = biasAll + (long long)e * sBias + blockIdx.x * 128;

  const int tid = threadIdx.x;
  const int lane = tid & 63;
  const int wid = tid >> 6;
  const int wr = (wid >> 1) * 64;
  const int wc = (wid & 1) * 64;
  const int l15 = lane & 15;
  const int khi = lane >> 4;          // 0..3
  const int swz = lane & 7;

  // staging lane geometry: chunk = 1KB = 8 rows x 128B; slot permuted by row&7
  const int srow = lane >> 3;                 // 0..7
  const int sslot = (lane & 7) ^ srow;        // permuted 16B slot

  f32x4 acc[4][4];
#pragma unroll
  for (int m = 0; m < 4; ++m)
#pragma unroll
    for (int n = 0; n < 4; ++n) acc[m][n] = (f32x4){0.f, 0.f, 0.f, 0.f};

  const int nK = Kd >> 6;
  for (int kt = 0; kt < nK; ++kt) {
    const int kb = kt << 6;
#pragma unroll
    for (int j = 0; j < 4; ++j) {
      const int c = wid * 4 + j;              // chunk 0..15
      const long long rowg = 8 * c + srow;
      gload_lds16(A  + rowg * Kd + kb + sslot * 8, &Alds[c * 512]);
      gload_lds16(Bt + rowg * Kd + kb + sslot * 8, &Blds[c * 512]);
    }
    __syncthreads();
#pragma unroll
    for (int kk = 0; kk < 2; ++kk) {
      bf16x8 af[4], bfv[4];
#pragma unroll
      for (int m = 0; m < 4; ++m)
        af[m] = *(const bf16x8*)&Alds[(wr + m * 16 + l15) * 64 + (((kk * 4 + khi) ^ swz) << 3)];
#pragma unroll
      for (int n = 0; n < 4; ++n)
        bfv[n] = *(const bf16x8*)&Blds[(wc + n * 16 + l15) * 64 + (((kk * 4 + khi) ^ swz) << 3)];
#pragma unroll
      for (int m = 0; m < 4; ++m)
#pragma unroll
        for (int n = 0; n < 4; ++n)
          acc[m][n] = __builtin_amdgcn_mfma_f32_16x16x32_bf16(af[m], bfv[n], acc[m][n], 0, 0, 0);
    }
    __syncthreads();
  }

  const int crow = khi * 4;
#pragma unroll
  for (int m = 0; m < 4; ++m) {
#pragma unroll
    for (int n = 0; n < 4; ++n) {
      const long long col = (long long)blockIdx.x * 128 + wc + n * 16 + l15;
      const float bvv = bias[wc + n * 16 + l15];
#pragma unroll
      for (int j = 0; j < 4; ++j) {
        const long long row = (long long)blockIdx.y * 128 + wr + m * 16 + crow + j;
        float v = acc[m][n][j] + bvv;
        if (GELU) v = 0.5f * v * (1.f + erff(v * 0.70710678118654752f));
        if (OUT_BF16)
          ((unsigned short*)OutAll)[(long long)e * sO + row * N + col] = f2bf(v);
        else
          ((float*)OutAll)[(long long)e * sO + row * N + col] = v;
      }
    }
  }
}

// ---------------- combine ----------------
__global__ __launch_bounds__(256) void combine_kernel(
    const float* __restrict__ y, const int* __restrict__ topi,
    const float* __restrict__ topw, const int* __restrict__ pos,
    const int* __restrict__ within, float* __restrict__ out) {
  int t = blockIdx.x;
  int i = threadIdx.x * 4;
  float4 r = {0.f, 0.f, 0.f, 0.f};
#pragma unroll
  for (int k = 0; k < 2; ++k) {
    int a = k * T + t;
    if (within[a]) {
      int e = topi[t * 2 + k];
      int p = pos[a];
      float w = topw[t * 2 + k];
      const float* yr = y + ((size_t)e * CP + p) * Dm;
      float4 v = *(const float4*)(yr + i);
      r.x += w * v.x; r.y += w * v.y; r.z += w * v.z; r.w += w * v.w;
    }
  }
  *(float4*)(out + (size_t)t * Dm + i) = r;
}

extern "C" void kernel_launch(void* const* d_in, const int* in_sizes, int n_in,
                              void* d_out, int out_size, void* d_ws, size_t ws_size,
                              hipStream_t stream) {
  const float* x  = (const float*)d_in[0];
  const float* Wg = (const float*)d_in[1];
  const float* W1 = (const float*)d_in[2];
  const float* b1 = (const float*)d_in[3];
  const float* W2 = (const float*)d_in[4];
  const float* b2 = (const float*)d_in[5];
  float* out = (float*)d_out;

  char* ws = (char*)d_ws;
  const size_t sz_h = (size_t)NE * CP * Hm * 2;        // 75.5 MB  (bf16 h)
  const size_t sz_y = (size_t)NE * CP * Dm * 4;        // 37.7 MB  (f32 y; buf bf16 aliases front)
  const size_t sz_wt_full = (size_t)NE * Hm * Dm * 2;  // 67.1 MB
  const size_t needA = sz_h + sz_y + sz_wt_full + (size_t)2 * T * 16;
  const int EB = (ws_size >= needA) ? NE : 2;          // experts per weight batch

  unsigned short* h = (unsigned short*)ws;
  char* yreg = ws + sz_h;
  unsigned short* buf = (unsigned short*)yreg;         // bf16 [E][CP][Dm], dead after GEMM1
  float* y = (float*)yreg;                             // f32  [E][CP][Dm], written by GEMM2
  unsigned short* Wt = (unsigned short*)(ws + sz_h + sz_y);
  char* smallp = ws + sz_h + sz_y + (size_t)EB * Hm * Dm * 2;
  int* topi   = (int*)smallp;
  float* topw = (float*)(topi + 2 * T);
  int* pos    = (int*)(topw + 2 * T);
  int* within = pos + 2 * T;

  router_kernel<<<T / 4, 256, 0, stream>>>(x, Wg, topi, topw);
  dispatch_kernel<<<1, 64, 0, stream>>>(topi, pos, within);
  scatter_kernel<<<2 * T, 256, 0, stream>>>(x, topi, pos, within, buf);

  // ---- stage 1: h = gelu(buf @ W1 + b1) ----
  for (int e0 = 0; e0 < NE; e0 += EB) {
    transpose_kernel<<<dim3(Hm / 32, Dm / 64, EB), 256, 0, stream>>>(
        W1 + (size_t)e0 * Dm * Hm, Wt, Dm, Hm);
    gemm_bt_kernel<true, true><<<dim3(Hm / 128, CP / 128, EB), 256, 0, stream>>>(
        buf + (size_t)e0 * CP * Dm, Wt, b1 + (size_t)e0 * Hm,
        (void*)(h + (size_t)e0 * CP * Hm),
        Dm, Hm, (long long)CP * Dm, (long long)Hm * Dm, (long long)CP * Hm, Hm);
  }
  // ---- stage 2: y = h @ W2 + b2 ----  (y overwrites buf; buf is dead)
  for (int e0 = 0; e0 < NE; e0 += EB) {
    transpose_kernel<<<dim3(Dm / 32, Hm / 64, EB), 256, 0, stream>>>(
        W2 + (size_t)e0 * Hm * Dm, Wt, Hm, Dm);
    gemm_bt_kernel<false, false><<<dim3(Dm / 128, CP / 128, EB), 256, 0, stream>>>(
        h + (size_t)e0 * CP * Hm, Wt, b2 + (size_t)e0 * Dm,
        (void*)(y + (size_t)e0 * CP * Dm),
        Hm, Dm, (long long)CP * Hm, (long long)Dm * Hm, (long long)CP * Dm, Dm);
  }

  combine_kernel<<<T, 256, 0, stream>>>(y, topi, topw, pos, within, out);
}

// Round 3
// 344.126 us; speedup vs baseline: 1.3361x; 1.1553x over previous
//
#include <hip/hip_runtime.h>

typedef __attribute__((ext_vector_type(8))) __bf16 bf16x8;
typedef __attribute__((ext_vector_type(4))) float f32x4;

constexpr int T  = 4096;   // tokens
constexpr int Dm = 1024;   // model dim
constexpr int Hm = 4096;   // hidden dim
constexpr int NE = 8;      // experts
constexpr int CAP = 1075;  // capacity  round(2*4096*1.05/8)
constexpr int CP  = 1152;  // capacity padded to 9*128

static __device__ __forceinline__ unsigned short f2bf(float f) {
  unsigned int u = __float_as_uint(f);
  u += 0x7FFFu + ((u >> 16) & 1u);   // RNE
  return (unsigned short)(u >> 16);
}

static __device__ __forceinline__ void gload_lds16(const void* g, void* l) {
  __builtin_amdgcn_global_load_lds(
      (const __attribute__((address_space(1))) void*)g,
      (__attribute__((address_space(3))) void*)l, 16, 0, 0);
}

// ---------------- router: logits = x @ Wg^T, softmax, top-2 ----------------
__global__ __launch_bounds__(256) void router_kernel(
    const float* __restrict__ x, const float* __restrict__ Wg,
    int* __restrict__ topi, float* __restrict__ topw) {
  int t = blockIdx.x * 4 + (threadIdx.x >> 6);
  int lane = threadIdx.x & 63;
  const float* xr = x + (size_t)t * Dm;
  float acc[NE];
#pragma unroll
  for (int e = 0; e < NE; ++e) acc[e] = 0.f;
  for (int i = lane * 4; i < Dm; i += 256) {
    float4 xv = *(const float4*)(xr + i);
#pragma unroll
    for (int e = 0; e < NE; ++e) {
      float4 wv = *(const float4*)(Wg + e * Dm + i);
      acc[e] += xv.x * wv.x + xv.y * wv.y + xv.z * wv.z + xv.w * wv.w;
    }
  }
#pragma unroll
  for (int off = 32; off > 0; off >>= 1) {
#pragma unroll
    for (int e = 0; e < NE; ++e) acc[e] += __shfl_xor(acc[e], off, 64);
  }
  if (lane == 0) {
    float mx = acc[0];
#pragma unroll
    for (int e = 1; e < NE; ++e) mx = fmaxf(mx, acc[e]);
    float g[NE];
    float s = 0.f;
#pragma unroll
    for (int e = 0; e < NE; ++e) { g[e] = expf(acc[e] - mx); s += g[e]; }
    int i0 = 0; float v0 = g[0];
#pragma unroll
    for (int e = 1; e < NE; ++e) if (g[e] > v0) { v0 = g[e]; i0 = e; }
    int i1 = -1; float v1 = -1e30f;
#pragma unroll
    for (int e = 0; e < NE; ++e) {
      if (e == i0) continue;
      if (g[e] > v1) { v1 = g[e]; i1 = e; }
    }
    float inv = 1.f / s;
    topi[t * 2] = i0; topi[t * 2 + 1] = i1;
    topw[t * 2] = v0 * inv; topw[t * 2 + 1] = v1 * inv;
  }
}

// ------------- dispatch: parallel slot-major multi-counter prefix scan -------------
// 1 block x 1024 threads, 8 assignments/thread. Packed 8x16-bit counters in 2 u64.
__global__ __launch_bounds__(1024) void dispatch_scan_kernel(
    const int* __restrict__ topi, int* __restrict__ pos, int* __restrict__ within) {
  __shared__ unsigned long long sc0[1024];
  __shared__ unsigned long long sc1[1024];
  const int tid = threadIdx.x;
  int myE[8];
  unsigned long long w0 = 0, w1 = 0;
#pragma unroll
  for (int j = 0; j < 8; ++j) {
    int a = tid * 8 + j;
    int k = a >> 12;
    int t = a & (T - 1);
    int e = topi[t * 2 + k];
    myE[j] = e;
    unsigned long long inc = 1ULL << (16 * (e & 3));
    if (e < 4) w0 += inc; else w1 += inc;
  }
  const unsigned long long l0 = w0, l1 = w1;  // local counts
  sc0[tid] = w0; sc1[tid] = w1;
  __syncthreads();
  for (int off = 1; off < 1024; off <<= 1) {
    unsigned long long a0 = 0, a1 = 0;
    if (tid >= off) { a0 = sc0[tid - off]; a1 = sc1[tid - off]; }
    __syncthreads();
    w0 += a0; w1 += a1;
    sc0[tid] = w0; sc1[tid] = w1;
    __syncthreads();
  }
  // exclusive base for this thread
  unsigned long long e0 = w0 - l0, e1 = w1 - l1;
#pragma unroll
  for (int j = 0; j < 8; ++j) {
    int a = tid * 8 + j;
    int e = myE[j];
    int sh = 16 * (e & 3);
    int p;
    if (e < 4) { p = (int)((e0 >> sh) & 0xFFFF); e0 += 1ULL << sh; }
    else       { p = (int)((e1 >> sh) & 0xFFFF); e1 += 1ULL << sh; }
    pos[a] = p;
    within[a] = (p < CAP) ? 1 : 0;
  }
}

// ---------------- scatter accepted tokens -> buf[e][p] (bf16) ----------------
__global__ __launch_bounds__(256) void scatter_kernel(
    const float* __restrict__ x, const int* __restrict__ topi,
    const int* __restrict__ pos, const int* __restrict__ within,
    unsigned short* __restrict__ buf) {
  int a = blockIdx.x;
  if (!within[a]) return;
  int k = a >> 12, t = a & (T - 1);
  int e = topi[t * 2 + k];
  int p = pos[a];
  const float* src = x + (size_t)t * Dm;
  unsigned short* dst = buf + ((size_t)e * CP + p) * Dm;
  int i = threadIdx.x * 4;
  float4 v = *(const float4*)(src + i);
  ushort4 o;
  o.x = f2bf(v.x); o.y = f2bf(v.y); o.z = f2bf(v.z); o.w = f2bf(v.w);
  *(ushort4*)(dst + i) = o;
}

// ------------- transpose+convert: W [E?][Kd][N] f32 -> Wt [E?][N][Kd] bf16 -------------
__global__ __launch_bounds__(256) void transpose_kernel(
    const float* __restrict__ W, unsigned short* __restrict__ Wt,
    int Kd, int N) {
  __shared__ float tile[64][33];
  const int e = blockIdx.z;
  const int n0 = blockIdx.x * 32;
  const int k0 = blockIdx.y * 64;
  const float* src = W + ((long long)e * Kd + k0) * N + n0;
  const int tid = threadIdx.x;
  const int r = tid >> 3;            // 0..31
  const int c4 = (tid & 7) * 4;
#pragma unroll
  for (int hh = 0; hh < 2; ++hh) {
    float4 v = *(const float4*)(src + (long long)(r + 32 * hh) * N + c4);
    tile[r + 32 * hh][c4] = v.x; tile[r + 32 * hh][c4 + 1] = v.y;
    tile[r + 32 * hh][c4 + 2] = v.z; tile[r + 32 * hh][c4 + 3] = v.w;
  }
  __syncthreads();
  const int n = tid >> 4;            // 0..15
  const int k4 = (tid & 15) * 4;
  unsigned short* dst = Wt + ((long long)e * N + n0) * Kd + k0;
#pragma unroll
  for (int hh = 0; hh < 2; ++hh) {
    int nn = n + 16 * hh;
    ushort4 o;
    o.x = f2bf(tile[k4][nn]);     o.y = f2bf(tile[k4 + 1][nn]);
    o.z = f2bf(tile[k4 + 2][nn]); o.w = f2bf(tile[k4 + 3][nn]);
    *(ushort4*)(dst + (long long)nn * Kd + k4) = o;
  }
}

// ---------------- GEMM: C[M][N] = A[M][K](bf16) @ Bt[N][K](bf16)^T + bias ----------------
// m97 structure + 1-D grid with expert->XCD pinning (e = lin % eb) and
// m-fastest ordering within expert for L2 reuse of the A panel / B co-sharing.
template <bool GELU, bool OUT_BF16>
__global__ __launch_bounds__(256) void gemm_bt_kernel(
    const unsigned short* __restrict__ Aall, const unsigned short* __restrict__ Btall,
    const float* __restrict__ biasAll, void* __restrict__ OutAll,
    int Kd, int N, long long sA, long long sB, long long sO, int sBias,
    int eb, int nM) {
  __shared__ unsigned short Alds[128 * 64];
  __shared__ unsigned short Blds[128 * 64];

  const int lin = blockIdx.x;
  const int e = lin % eb;         // XCD pin when eb==8
  const int q = lin / eb;
  const int mb = q % nM;          // m fastest: 9 blocks share one B panel
  const int nb = q / nM;

  const unsigned short* A  = Aall  + (long long)e * sA + (long long)mb * 128 * Kd;
  const unsigned short* Bt = Btall + (long long)e * sB + (long long)nb * 128 * Kd;
  const float* bias = biasAll + (long long)e * sBias + nb * 128;

  const int tid = threadIdx.x;
  const int lane = tid & 63;
  const int wid = tid >> 6;
  const int wr = (wid >> 1) * 64;
  const int wc = (wid & 1) * 64;
  const int l15 = lane & 15;
  const int khi = lane >> 4;          // 0..3
  const int swz = lane & 7;

  // staging lane geometry: chunk = 1KB = 8 rows x 128B; slot permuted by row&7
  const int srow = lane >> 3;                 // 0..7
  const int sslot = (lane & 7) ^ srow;        // permuted 16B slot

  f32x4 acc[4][4];
#pragma unroll
  for (int m = 0; m < 4; ++m)
#pragma unroll
    for (int n = 0; n < 4; ++n) acc[m][n] = (f32x4){0.f, 0.f, 0.f, 0.f};

  const int nK = Kd >> 6;
  for (int kt = 0; kt < nK; ++kt) {
    const int kb = kt << 6;
#pragma unroll
    for (int j = 0; j < 4; ++j) {
      const int c = wid * 4 + j;              // chunk 0..15
      const long long rowg = 8 * c + srow;
      gload_lds16(A  + rowg * Kd + kb + sslot * 8, &Alds[c * 512]);
      gload_lds16(Bt + rowg * Kd + kb + sslot * 8, &Blds[c * 512]);
    }
    __syncthreads();
#pragma unroll
    for (int kk = 0; kk < 2; ++kk) {
      bf16x8 af[4], bfv[4];
#pragma unroll
      for (int m = 0; m < 4; ++m)
        af[m] = *(const bf16x8*)&Alds[(wr + m * 16 + l15) * 64 + (((kk * 4 + khi) ^ swz) << 3)];
#pragma unroll
      for (int n = 0; n < 4; ++n)
        bfv[n] = *(const bf16x8*)&Blds[(wc + n * 16 + l15) * 64 + (((kk * 4 + khi) ^ swz) << 3)];
#pragma unroll
      for (int m = 0; m < 4; ++m)
#pragma unroll
        for (int n = 0; n < 4; ++n)
          acc[m][n] = __builtin_amdgcn_mfma_f32_16x16x32_bf16(af[m], bfv[n], acc[m][n], 0, 0, 0);
    }
    __syncthreads();
  }

  const int crow = khi * 4;
#pragma unroll
  for (int m = 0; m < 4; ++m) {
#pragma unroll
    for (int n = 0; n < 4; ++n) {
      const long long col = (long long)nb * 128 + wc + n * 16 + l15;
      const float bvv = bias[wc + n * 16 + l15];
#pragma unroll
      for (int j = 0; j < 4; ++j) {
        const long long row = (long long)mb * 128 + wr + m * 16 + crow + j;
        float v = acc[m][n][j] + bvv;
        if (GELU) v = 0.5f * v * (1.f + erff(v * 0.70710678118654752f));
        if (OUT_BF16)
          ((unsigned short*)OutAll)[(long long)e * sO + row * N + col] = f2bf(v);
        else
          ((float*)OutAll)[(long long)e * sO + row * N + col] = v;
      }
    }
  }
}

// ---------------- combine ----------------
__global__ __launch_bounds__(256) void combine_kernel(
    const float* __restrict__ y, const int* __restrict__ topi,
    const float* __restrict__ topw, const int* __restrict__ pos,
    const int* __restrict__ within, float* __restrict__ out) {
  int t = blockIdx.x;
  int i = threadIdx.x * 4;
  float4 r = {0.f, 0.f, 0.f, 0.f};
#pragma unroll
  for (int k = 0; k < 2; ++k) {
    int a = k * T + t;
    if (within[a]) {
      int e = topi[t * 2 + k];
      int p = pos[a];
      float w = topw[t * 2 + k];
      const float* yr = y + ((size_t)e * CP + p) * Dm;
      float4 v = *(const float4*)(yr + i);
      r.x += w * v.x; r.y += w * v.y; r.z += w * v.z; r.w += w * v.w;
    }
  }
  *(float4*)(out + (size_t)t * Dm + i) = r;
}

extern "C" void kernel_launch(void* const* d_in, const int* in_sizes, int n_in,
                              void* d_out, int out_size, void* d_ws, size_t ws_size,
                              hipStream_t stream) {
  const float* x  = (const float*)d_in[0];
  const float* Wg = (const float*)d_in[1];
  const float* W1 = (const float*)d_in[2];
  const float* b1 = (const float*)d_in[3];
  const float* W2 = (const float*)d_in[4];
  const float* b2 = (const float*)d_in[5];
  float* out = (float*)d_out;

  char* ws = (char*)d_ws;
  const size_t sz_h = (size_t)NE * CP * Hm * 2;        // 75.5 MB  (bf16 h)
  const size_t sz_y = (size_t)NE * CP * Dm * 4;        // 37.7 MB  (f32 y; buf bf16 aliases front)
  const size_t sz_wt_full = (size_t)NE * Hm * Dm * 2;  // 67.1 MB
  const size_t needA = sz_h + sz_y + sz_wt_full + (size_t)2 * T * 16;
  const int EB = (ws_size >= needA) ? NE : 2;          // experts per weight batch

  unsigned short* h = (unsigned short*)ws;
  char* yreg = ws + sz_h;
  unsigned short* buf = (unsigned short*)yreg;         // bf16 [E][CP][Dm], dead after GEMM1
  float* y = (float*)yreg;                             // f32  [E][CP][Dm], written by GEMM2
  unsigned short* Wt = (unsigned short*)(ws + sz_h + sz_y);
  char* smallp = ws + sz_h + sz_y + (size_t)EB * Hm * Dm * 2;
  int* topi   = (int*)smallp;
  float* topw = (float*)(topi + 2 * T);
  int* pos    = (int*)(topw + 2 * T);
  int* within = pos + 2 * T;

  router_kernel<<<T / 4, 256, 0, stream>>>(x, Wg, topi, topw);
  dispatch_scan_kernel<<<1, 1024, 0, stream>>>(topi, pos, within);
  scatter_kernel<<<2 * T, 256, 0, stream>>>(x, topi, pos, within, buf);

  const int nM = CP / 128;  // 9
  // ---- stage 1: h = gelu(buf @ W1 + b1) ----
  for (int e0 = 0; e0 < NE; e0 += EB) {
    transpose_kernel<<<dim3(Hm / 32, Dm / 64, EB), 256, 0, stream>>>(
        W1 + (size_t)e0 * Dm * Hm, Wt, Dm, Hm);
    gemm_bt_kernel<true, true><<<EB * nM * (Hm / 128), 256, 0, stream>>>(
        buf + (size_t)e0 * CP * Dm, Wt, b1 + (size_t)e0 * Hm,
        (void*)(h + (size_t)e0 * CP * Hm),
        Dm, Hm, (long long)CP * Dm, (long long)Hm * Dm, (long long)CP * Hm, Hm,
        EB, nM);
  }
  // ---- stage 2: y = h @ W2 + b2 ----  (y overwrites buf; buf is dead)
  for (int e0 = 0; e0 < NE; e0 += EB) {
    transpose_kernel<<<dim3(Dm / 32, Hm / 64, EB), 256, 0, stream>>>(
        W2 + (size_t)e0 * Hm * Dm, Wt, Hm, Dm);
    gemm_bt_kernel<false, false><<<EB * nM * (Dm / 128), 256, 0, stream>>>(
        h + (size_t)e0 * CP * Hm, Wt, b2 + (size_t)e0 * Dm,
        (void*)(y + (size_t)e0 * CP * Dm),
        Hm, Dm, (long long)CP * Hm, (long long)Dm * Hm, (long long)CP * Dm, Dm,
        EB, nM);
  }

  combine_kernel<<<T, 256, 0, stream>>>(y, topi, topw, pos, within, out);
}